// Round 1
// 457.320 us; speedup vs baseline: 1.0679x; 1.0679x over previous
//
#include <hip/hip_runtime.h>
#include <cmath>

#define EPS_BN 1e-5f
#define EPS_SM 1e-16f

typedef _Float16 f16x8 __attribute__((ext_vector_type(8)));
typedef _Float16 f16x4 __attribute__((ext_vector_type(4)));
typedef _Float16 h2 __attribute__((ext_vector_type(2)));
typedef float f32x4 __attribute__((ext_vector_type(4)));
typedef int int2a __attribute__((ext_vector_type(2), aligned(4)));
typedef int int4a __attribute__((ext_vector_type(4), aligned(4)));
union F4 { float4 v; float a[4]; };
union H4 { f16x4 v; h2 p[2]; };

// ============================ CSR build ============================
__global__ void hist_kernel(const int* __restrict__ edst, int* __restrict__ deg, int E) {
    int e = blockIdx.x * 256 + threadIdx.x;
    if (e < E) atomicAdd(&deg[edst[e]], 1);
}

__global__ void scan1_kernel(const int* __restrict__ deg, int* __restrict__ row_ptr,
                             int* __restrict__ bsum, int N) {
    __shared__ int s[256];
    int t = threadIdx.x;
    int i = blockIdx.x * 256 + t;
    int v = (i < N) ? deg[i] : 0;
    s[t] = v; __syncthreads();
    for (int off = 1; off < 256; off <<= 1) {
        int x = (t >= off) ? s[t - off] : 0;
        __syncthreads();
        s[t] += x;
        __syncthreads();
    }
    if (i < N) row_ptr[i] = s[t] - v;   // exclusive partial
    if (t == 255) bsum[blockIdx.x] = s[t];
}

__global__ void scan2_kernel(int* __restrict__ bsum, int nb) {
    __shared__ int s[1024];
    int t = threadIdx.x;
    int v = (t < nb) ? bsum[t] : 0;
    s[t] = v; __syncthreads();
    for (int off = 1; off < 1024; off <<= 1) {
        int x = (t >= off) ? s[t - off] : 0;
        __syncthreads();
        s[t] += x;
        __syncthreads();
    }
    if (t < nb) bsum[t] = s[t] - v;     // exclusive
}

__global__ void scan3_kernel(int* __restrict__ row_ptr, int* __restrict__ cursor,
                             const int* __restrict__ bsum, int N, int E) {
    int i = blockIdx.x * 256 + threadIdx.x;
    if (i < N) {
        int v = row_ptr[i] + bsum[blockIdx.x];
        row_ptr[i] = v;
        cursor[i] = v;
    } else if (i == N) {
        row_ptr[N] = E;
    }
}

// ============================ merged setup: zero deg | Qm3 | gptr ============================
__global__ void setup_kernel(int* __restrict__ deg, int N, int nb1,
                             const float* __restrict__ convwe, const float* __restrict__ atte,
                             float* __restrict__ Qm3,
                             const int* __restrict__ batch, int* __restrict__ gptr, int G) {
    int b = blockIdx.x;
    int t = threadIdx.x;
    if (b < nb1) {
        int i = b * 256 + t;
        if (i < N) deg[i] = 0;
    } else if (b == nb1) {
        if (t >= 96) return;
        int l = t >> 5, f = (t >> 2) & 7, hh = t & 3;
        const float* we = convwe + (size_t)l * 8 * 256;
        const float* av = atte + (size_t)l * 256;
        float acc = 0.f;
        for (int c = 0; c < 64; c++) acc += we[f * 256 + hh * 64 + c] * av[hh * 64 + c];
        Qm3[t] = acc;
    } else {
        int g = (b - nb1 - 1) * 256 + t;
        if (g > G) return;
        int lo = 0, hi = N;
        while (lo < hi) { int mid = (lo + hi) >> 1; if (batch[mid] < g) lo = mid + 1; else hi = mid; }
        gptr[g] = lo;
    }
}

// scatter edges to CSR order: src_csr[p] = src; ae_csr record per edge,
// interleaved layout [p][3 layers][4 heads] f16 (24 B/edge -> single cache line write)
__global__ void scatter_kernel(const int* __restrict__ esrc, const int* __restrict__ edst,
                               const float* __restrict__ edge_attr, const float* __restrict__ Qm3,
                               int* __restrict__ cursor, int* __restrict__ src_csr,
                               _Float16* __restrict__ ae_csr, int E) {
    __shared__ float q[96];
    int t = threadIdx.x;
    if (t < 96) q[t] = Qm3[t];
    __syncthreads();
    int e = blockIdx.x * 256 + t;
    if (e >= E) return;
    int src = esrc[e];
    int p = atomicAdd(&cursor[edst[e]], 1);
    src_csr[p] = src;
    F4 ea0, ea1;
    ea0.v = ((const float4*)edge_attr)[(size_t)e * 2];
    ea1.v = ((const float4*)edge_attr)[(size_t)e * 2 + 1];
#pragma unroll
    for (int l = 0; l < 3; l++) {
        const float* ql = q + l * 32;
        f16x4 r;
#pragma unroll
        for (int hh = 0; hh < 4; hh++) {
            float acc = ea0.a[0] * ql[0 * 4 + hh] + ea0.a[1] * ql[1 * 4 + hh]
                      + ea0.a[2] * ql[2 * 4 + hh] + ea0.a[3] * ql[3 * 4 + hh]
                      + ea1.a[0] * ql[4 * 4 + hh] + ea1.a[1] * ql[5 * 4 + hh]
                      + ea1.a[2] * ql[6 * 4 + hh] + ea1.a[3] * ql[7 * 4 + hh];
            r[hh] = (_Float16)acc;
        }
        *(f16x4*)(ae_csr + (size_t)p * 12 + l * 4) = r;
    }
}

// ============================ input projection (h16 + BN partials) ============================
__global__ void proj_kernel(const float* __restrict__ x, const float* __restrict__ lin_w,
                            const float* __restrict__ lin_b,
                            _Float16* __restrict__ h16, float* __restrict__ bnpart, int N) {
    __shared__ float Xs[64 * 32];
    __shared__ float ls[256], lq[256];
    int t = threadIdx.x;
    int col = t & 63, sub = t >> 6;
    float w[32];
#pragma unroll
    for (int k = 0; k < 32; k++) w[k] = lin_w[k * 64 + col];
    float b = lin_b[col];
    int r0 = blockIdx.x * 64;
    const float4* xg = (const float4*)(x + (size_t)r0 * 32);
    float4* Xs4 = (float4*)Xs;
    size_t totf4 = (size_t)N * 8;
#pragma unroll
    for (int i = 0; i < 2; i++) {
        int idx = t + i * 256;
        size_t gidx = (size_t)r0 * 8 + idx;
        Xs4[idx] = (gidx < totf4) ? xg[idx] : make_float4(0.f, 0.f, 0.f, 0.f);
    }
    __syncthreads();
    float ps = 0.f, pq = 0.f;
    for (int rr = sub; rr < 64; rr += 4) {
        int r = r0 + rr;
        if (r >= N) break;
        float acc = b;
        const float4* a4p = (const float4*)(Xs + rr * 32);
#pragma unroll
        for (int kk = 0; kk < 8; kk++) {
            float4 a4 = a4p[kk];
            acc += a4.x * w[kk * 4] + a4.y * w[kk * 4 + 1] + a4.z * w[kk * 4 + 2] + a4.w * w[kk * 4 + 3];
        }
        float hv = fmaxf(acc, 0.f);
        h16[(size_t)r * 64 + col] = (_Float16)hv;
        ps += hv; pq += hv * hv;
    }
    ls[t] = ps; lq[t] = pq;
    __syncthreads();
    if (t < 64) {
        bnpart[(size_t)blockIdx.x * 128 + t] = ls[t] + ls[t + 64] + ls[t + 128] + ls[t + 192];
        bnpart[(size_t)blockIdx.x * 128 + 64 + t] = lq[t] + lq[t + 64] + lq[t + 128] + lq[t + 192];
    }
}

// reduce bnpart over blocks: red[stat] = sum_b bnpart[b][stat], stat = blockIdx (128 blocks)
__global__ void bn_reduce_kernel(const float* __restrict__ bnpart, int nb, float* __restrict__ red) {
    __shared__ float s[256];
    int stat = blockIdx.x;
    float acc = 0.f;
    for (int j = threadIdx.x; j < nb; j += 256) acc += bnpart[(size_t)j * 128 + stat];
    s[threadIdx.x] = acc;
    __syncthreads();
    for (int off = 128; off >= 1; off >>= 1) {
        if (threadIdx.x < off) s[threadIdx.x] += s[threadIdx.x + off];
        __syncthreads();
    }
    if (threadIdx.x == 0) red[stat] = s[0];
}

// ============================ fold (parallel) ============================
__global__ void fold2_kernel(const float* __restrict__ red,
                             const float* __restrict__ gamma, const float* __restrict__ beta,
                             const float* __restrict__ convw,
                             const float* __restrict__ atts, const float* __restrict__ attd,
                             _Float16* __restrict__ Wt, float* __restrict__ bpb,
                             _Float16* __restrict__ Pt, float* __restrict__ cs,
                             float invN) {
    __shared__ float scl[64], sft[64], bs[256];
    int t = threadIdx.x;
    if (t < 64) {
        float mu = red[t] * invN;
        float var = fmaxf(red[64 + t] * invN - mu * mu, 0.f);
        float sc = gamma[t] / sqrtf(var + EPS_BN);
        scl[t] = sc;
        sft[t] = beta[t] - mu * sc;
    }
    __syncthreads();
    int b = blockIdx.x;
    if (b < 64) {
        int col = b;
        int c = t >> 2, hh = t & 3;
        Wt[col * 256 + t] = (_Float16)(0.25f * scl[c] * convw[c * 256 + hh * 64 + col]);
    } else if (b == 64) {
        for (int idx = t; idx < 512; idx += 256) {
            int k = idx >> 3, o = idx & 7, hh = o & 3;
            const float* av = (o < 4) ? atts : attd;
            float acc = 0.f;
            for (int c2 = 0; c2 < 64; c2++) acc += convw[k * 256 + hh * 64 + c2] * av[hh * 64 + c2];
            Pt[o * 64 + k] = (_Float16)(scl[k] * acc);
        }
        for (int idx = t; idx < 512; idx += 256) Pt[512 + idx] = (_Float16)0.f;
    } else {
        float bacc = 0.f;
        for (int k = 0; k < 64; k++) bacc += sft[k] * convw[k * 256 + t];
        bpb[t] = bacc;
        bs[t] = bacc;
        __syncthreads();
        if (t < 8) {
            int hh = t & 3;
            const float* av = (t < 4) ? atts : attd;
            float acc = 0.f;
            for (int c2 = 0; c2 < 64; c2++) acc += bs[hh * 64 + c2] * av[hh * 64 + c2];
            cs[t] = acc;
        }
    }
}

// ============================ per-node attention logits via MFMA ============================
__global__ __launch_bounds__(256) void att_node_kernel(
        const _Float16* __restrict__ h16, const _Float16* __restrict__ Pt,
        const float* __restrict__ cs, _Float16* __restrict__ a_sd, int N) {
    int t = threadIdx.x;
    int wv = t >> 6, lane = t & 63;
    int m = lane & 15, quad = lane >> 4, kb = quad * 8;
    int r0 = blockIdx.x * 64 + wv * 16;
    f16x8 b0 = *(const f16x8*)(Pt + m * 64 + kb);
    f16x8 b1 = *(const f16x8*)(Pt + m * 64 + 32 + kb);
    f16x8 a0 = {}, a1 = {};
    int rm = r0 + m;
    if (rm < N) {
        a0 = *(const f16x8*)(h16 + ((size_t)rm << 6) + kb);
        a1 = *(const f16x8*)(h16 + ((size_t)rm << 6) + 32 + kb);
    }
    f32x4 acc = {0.f, 0.f, 0.f, 0.f};
    acc = __builtin_amdgcn_mfma_f32_16x16x32_f16(a0, b0, acc, 0, 0, 0);
    acc = __builtin_amdgcn_mfma_f32_16x16x32_f16(a1, b1, acc, 0, 0, 0);
    if (m < 8) {
        float cso = cs[m];
#pragma unroll
        for (int reg = 0; reg < 4; reg++) {
            int rg = r0 + quad * 4 + reg;
            if (rg < N) a_sd[(size_t)rg * 8 + m] = (_Float16)(acc[reg] + cso);
        }
    }
}

// ============================ fused scores + aggregation + projection (MFMA) ============================
// 32-node tile per block, 4 waves; slot = 16 lanes owns TWO nodes. 4-edge chunks:
// one int4 src load, 4 independent 8B f16 h-row gathers (second pair gated on rem>2),
// all 16 lanes score one (edge, head) each, weights broadcast pre-packed {w,w} via
// ds_swizzle immediates (no bpermute index setup, no consumer-side cvt/pack),
// per-lane exp partials reduced to dd once after the loop. MFMA projects two 16-row tiles.
__global__ __launch_bounds__(256) void msg_proj_kernel(
        const int* __restrict__ row_ptr, const int* __restrict__ src_csr,
        const _Float16* __restrict__ ae_c, const _Float16* __restrict__ a_sd,
        const _Float16* __restrict__ h16_in,
        const _Float16* __restrict__ Wt, const float* __restrict__ bpb,
        const float* __restrict__ bias,
        _Float16* __restrict__ h16_out, float* __restrict__ bnpart, int N) {
    __shared__ __attribute__((aligned(16))) _Float16 Aagg[32][264];
    __shared__ __attribute__((aligned(16))) float sals[32][4];
    int t = threadIdx.x;
    int wv = t >> 6, lane = t & 63;
    int colg = wv * 16 + (lane & 15);
    int kb = (lane >> 4) * 8;
    int slot = lane >> 4, c4 = lane & 15;
    int head = c4 & 3, j = c4 >> 2;
    int nb0 = blockIdx.x * 32;
    int rows[2] = {wv * 8 + slot, wv * 8 + slot + 4};

    float bpbc[4];
#pragma unroll
    for (int hh = 0; hh < 4; hh++) bpbc[hh] = bpb[hh * 64 + colg] * 0.25f;
    float bcol = bias[colg];

    h2 Acc[2][4][2];    // [node][head][channel-pair], fp16 packed
    float ddp[2];       // per-lane exp partial for this lane's (edge j, head)
    int p1v[2];
    float adv[2];
    int base0, base1;
#pragma unroll
    for (int u = 0; u < 2; u++) {
#pragma unroll
        for (int h = 0; h < 4; h++) {
            Acc[u][h][0] = (h2){(_Float16)0.f, (_Float16)0.f};
            Acc[u][h][1] = (h2){(_Float16)0.f, (_Float16)0.f};
        }
        ddp[u] = 0.f;
        int n = nb0 + rows[u];
        int p0 = 0, p1 = 0;
        if (n < N) { p0 = row_ptr[n]; p1 = row_ptr[n + 1]; }
        adv[u] = (p0 < p1) ? (float)a_sd[(size_t)n * 8 + 4 + head] : 0.f;
        p1v[u] = p1;
        if (u == 0) base0 = p0; else base1 = p0;
    }

// broadcast from lane (slot_base | i) to all 16 lanes of the slot (per-32-half pattern)
#define SWZ(i) __builtin_bit_cast(h2, __builtin_amdgcn_ds_swizzle(w32, (((i) << 5) | 0x10)))
#define EDGEACC(J, UU)                                                        \
        {                                                                     \
            h2 W0 = SWZ(4*(J)+0), W1 = SWZ(4*(J)+1);                          \
            h2 W2 = SWZ(4*(J)+2), W3 = SWZ(4*(J)+3);                          \
            Acc[u][0][0] += W0 * UU.p[0]; Acc[u][0][1] += W0 * UU.p[1];       \
            Acc[u][1][0] += W1 * UU.p[0]; Acc[u][1][1] += W1 * UU.p[1];       \
            Acc[u][2][0] += W2 * UU.p[0]; Acc[u][2][1] += W2 * UU.p[1];       \
            Acc[u][3][0] += W3 * UU.p[0]; Acc[u][3][1] += W3 * UU.p[1];       \
        }

    auto chunk4 = [&](int u, int base) {
        int rem = p1v[u] - base;          // >= 1 when called
        int4a sv = *(const int4a*)(src_csr + base);
        int s0 = sv.x;
        int s1 = rem > 1 ? sv.y : s0;
        int s2 = rem > 2 ? sv.z : s0;
        int s3 = rem > 3 ? sv.w : s0;
        H4 u0, u1;
        u0.v = *(const f16x4*)(h16_in + ((size_t)s0 << 6) + (c4 << 2));
        u1.v = *(const f16x4*)(h16_in + ((size_t)s1 << 6) + (c4 << 2));
        int myj = j < rem ? j : rem - 1;
        int mysrc = j == 0 ? s0 : (j == 1 ? s1 : (j == 2 ? s2 : s3));
        float myas = (float)a_sd[(size_t)mysrc * 8 + head];
        float aev = (float)ae_c[(size_t)(base + myj) * 12 + head];
        float sc = myas + adv[u] + aev;
        sc = sc > 0.f ? sc : 0.2f * sc;
        float ex = (j < rem) ? __expf(sc) : 0.f;
        ddp[u] += ex;
        _Float16 wh = (_Float16)ex;
        h2 wp; wp.x = wh; wp.y = wh;
        int w32 = __builtin_bit_cast(int, wp);
        EDGEACC(0, u0)
        EDGEACC(1, u1)
        if (rem > 2) {
            H4 u2, u3;
            u2.v = *(const f16x4*)(h16_in + ((size_t)s2 << 6) + (c4 << 2));
            u3.v = *(const f16x4*)(h16_in + ((size_t)s3 << 6) + (c4 << 2));
            EDGEACC(2, u2)
            EDGEACC(3, u3)
        }
    };

    while (base0 < p1v[0] || base1 < p1v[1]) {
        if (base0 < p1v[0]) chunk4(0, base0);
        if (base1 < p1v[1]) chunk4(1, base1);
        base0 += 4; base1 += 4;
    }
#undef EDGEACC
#undef SWZ

#pragma unroll
    for (int u = 0; u < 2; u++) {
        // reduce exp partials over j (lane bits 2,3), then broadcast per-head sums
        float d = ddp[u];
        d += __shfl_xor(d, 4);
        d += __shfl_xor(d, 8);
        int di = __builtin_bit_cast(int, d);
        float dh0 = __builtin_bit_cast(float, __builtin_amdgcn_ds_swizzle(di, (0 << 5) | 0x10));
        float dh1 = __builtin_bit_cast(float, __builtin_amdgcn_ds_swizzle(di, (1 << 5) | 0x10));
        float dh2 = __builtin_bit_cast(float, __builtin_amdgcn_ds_swizzle(di, (2 << 5) | 0x10));
        float dh3 = __builtin_bit_cast(float, __builtin_amdgcn_ds_swizzle(di, (3 << 5) | 0x10));
        float dharr[4] = {dh0, dh1, dh2, dh3};
        f16x8 v0, v1;
#pragma unroll
        for (int h = 0; h < 4; h++) {
            float dv = dharr[h];
            float invd = dv > 0.f ? 1.f / (dv + EPS_SM) : 0.f;
            _Float16 ih = (_Float16)invd;
            h2 IH = {ih, ih};
            h2 q0 = Acc[u][h][0] * IH;
            h2 q1 = Acc[u][h][1] * IH;
            v0[h] = q0.x; v0[4 + h] = q0.y;
            v1[h] = q1.x; v1[4 + h] = q1.y;
        }
        *(f16x8*)&Aagg[rows[u]][c4 * 16] = v0;
        *(f16x8*)&Aagg[rows[u]][c4 * 16 + 8] = v1;
        if (c4 == 0) {
            float4 sv2;
            sv2.x = dh0 / (dh0 + EPS_SM);
            sv2.y = dh1 / (dh1 + EPS_SM);
            sv2.z = dh2 / (dh2 + EPS_SM);
            sv2.w = dh3 / (dh3 + EPS_SM);
            *(float4*)&sals[rows[u]][0] = sv2;
        }
    }
    // B fragments loaded here (overlaps LDS drain before the barrier)
    f16x8 bfrag[8];
    const _Float16* wtp = Wt + (size_t)colg * 256 + kb;
#pragma unroll
    for (int ks = 0; ks < 8; ks++) bfrag[ks] = *(const f16x8*)(wtp + ks * 32);
    __syncthreads();

    // -------- MFMA phase: two 16-row tiles --------
    float ps = 0.f, pq = 0.f;
#pragma unroll
    for (int half = 0; half < 2; half++) {
        f32x4 acc = {0.f, 0.f, 0.f, 0.f};
        const _Float16* ap = &Aagg[half * 16 + (lane & 15)][kb];
#pragma unroll
        for (int ks = 0; ks < 8; ks++) {
            f16x8 af = *(const f16x8*)(ap + ks * 32);
            acc = __builtin_amdgcn_mfma_f32_16x16x32_f16(af, bfrag[ks], acc, 0, 0, 0);
        }
        int r0 = half * 16 + (lane >> 4) * 4;
#pragma unroll
        for (int reg = 0; reg < 4; reg++) {
            int rr = r0 + reg;
            int nn = nb0 + rr;
            if (nn < N) {
                float v = acc[reg] + sals[rr][0] * bpbc[0] + sals[rr][1] * bpbc[1]
                        + sals[rr][2] * bpbc[2] + sals[rr][3] * bpbc[3] + bcol;
                size_t idx = ((size_t)nn << 6) + colg;
                float hv = (float)h16_in[idx];
                float outv = fmaxf(v, 0.f) + hv;
                h16_out[idx] = (_Float16)outv;
                ps += outv;
                pq += outv * outv;
            }
        }
    }
    // reduce the 4 row-quads (lanes differing in bits 4,5) -> per-col BN partials
    ps += __shfl_xor(ps, 16); ps += __shfl_xor(ps, 32);
    pq += __shfl_xor(pq, 16); pq += __shfl_xor(pq, 32);
    if ((lane >> 4) == 0) {
        bnpart[(size_t)blockIdx.x * 128 + colg] = ps;
        bnpart[(size_t)blockIdx.x * 128 + 64 + colg] = pq;
    }
}

// ============================ pooling + FC head ============================
__global__ void pool_fc_kernel(const _Float16* __restrict__ h16, const int* __restrict__ gptr,
                               const float* __restrict__ fc1_w, const float* __restrict__ fc1_b,
                               const float* __restrict__ fc2_w, const float* __restrict__ fc2_b,
                               float* __restrict__ out, int G) {
    __shared__ float pool[4][64];
    int lane = threadIdx.x & 63, wv = threadIdx.x >> 6;
    int g = blockIdx.x * 4 + wv;
    float acc = 0.f;
    if (g < G) {
        int a = gptr[g], b = gptr[g + 1];
        for (int r = a; r < b; r++) acc += (float)h16[(size_t)r * 64 + lane];
    }
    pool[wv][lane] = acc;
    __syncthreads();
    float z1 = fc1_b[lane];
#pragma unroll 8
    for (int c = 0; c < 64; c++) z1 += pool[wv][c] * fc1_w[c * 64 + lane];
    z1 = fmaxf(z1, 0.f);
    float z2 = z1 * fc2_w[lane];
    z2 += __shfl_xor(z2, 1);
    z2 += __shfl_xor(z2, 2);
    z2 += __shfl_xor(z2, 4);
    z2 += __shfl_xor(z2, 8);
    z2 += __shfl_xor(z2, 16);
    z2 += __shfl_xor(z2, 32);
    if (g < G && lane == 0) out[g] = fmaxf(z2 + fc2_b[0], 0.f);
}

// ============================ host ============================
extern "C" void kernel_launch(void* const* d_in, const int* in_sizes, int n_in,
                              void* d_out, int out_size, void* d_ws, size_t ws_size,
                              hipStream_t stream) {
    const float* x         = (const float*)d_in[0];
    const int*   eindex    = (const int*)d_in[1];
    const float* edge_attr = (const float*)d_in[2];
    const int*   batch     = (const int*)d_in[3];
    const float* lin_w     = (const float*)d_in[4];
    const float* lin_b     = (const float*)d_in[5];
    const float* bn_gamma  = (const float*)d_in[6];
    const float* bn_beta   = (const float*)d_in[7];
    const float* conv_w    = (const float*)d_in[8];
    const float* conv_we   = (const float*)d_in[9];
    const float* att_src   = (const float*)d_in[10];
    const float* att_dst   = (const float*)d_in[11];
    const float* att_edge  = (const float*)d_in[12];
    const float* conv_bias = (const float*)d_in[13];
    const float* fc1_w     = (const float*)d_in[14];
    const float* fc1_b     = (const float*)d_in[15];
    const float* fc2_w     = (const float*)d_in[16];
    const float* fc2_b     = (const float*)d_in[17];
    float* out = (float*)d_out;

    int N = in_sizes[3];
    int E = in_sizes[1] / 2;
    int G = out_size;
    const int* esrc = eindex;
    const int* edst = eindex + E;

    char* wp = (char*)d_ws;
    auto carve = [&](size_t b) -> char* {
        char* p = wp;
        wp += (b + 511) & ~(size_t)511;
        return p;
    };
    _Float16*  h16b0  = (_Float16*)carve((size_t)N * 64 * 2);     // 25.6 MB
    _Float16*  h16b1  = (_Float16*)carve((size_t)N * 64 * 2);     // 25.6 MB
    _Float16*  a_sd   = (_Float16*)carve((size_t)N * 8 * 2);      //  3.2 MB
    _Float16*  ae_csr = (_Float16*)carve((size_t)E * 12 * 2);     //  9.6 MB ([p][3][4] f16)
    int*       src_csr= (int*)carve((size_t)(E + 4) * 4);         //  1.6 MB (+pad for tail)
    int*       deg    = (int*)carve((size_t)N * 4);
    int*       row_ptr= (int*)carve((size_t)(N + 1) * 4);
    int*       cursor = (int*)carve((size_t)N * 4);
    int*       bsum   = (int*)carve(4096);
    int*       gptr   = (int*)carve((size_t)(G + 1) * 4);
    float*     bpb    = (float*)carve(256 * 4);
    _Float16*  Pt     = (_Float16*)carve(1024 * 2);
    float*     cs     = (float*)carve(8 * 4);
    float*     Qm3    = (float*)carve(96 * 4);
    _Float16*  Wt     = (_Float16*)carve(64 * 256 * 2);
    float*     red    = (float*)carve(128 * 4);
    int nb1 = (N + 255) / 256;
    int nbP = (N + 63) / 64;
    int nTiles = (N + 31) / 32;
    int maxPart = nbP > nTiles ? nbP : nTiles;
    float*     bnpart = (float*)carve((size_t)maxPart * 128 * 4);

    // merged setup (zero deg | Qm3 | gptr), then CSR + scatter
    int gBlocks = (G + 1 + 255) / 256;
    setup_kernel<<<nb1 + 1 + gBlocks, 256, 0, stream>>>(deg, N, nb1, conv_we, att_edge, Qm3,
                                                        batch, gptr, G);
    hist_kernel<<<(E + 255) / 256, 256, 0, stream>>>(edst, deg, E);
    scan1_kernel<<<nb1, 256, 0, stream>>>(deg, row_ptr, bsum, N);
    scan2_kernel<<<1, 1024, 0, stream>>>(bsum, nb1);
    scan3_kernel<<<(N + 1 + 255) / 256, 256, 0, stream>>>(row_ptr, cursor, bsum, N, E);
    scatter_kernel<<<(E + 255) / 256, 256, 0, stream>>>(esrc, edst, edge_attr, Qm3,
                                                        cursor, src_csr, ae_csr, E);

    // input projection (+ BN partials for layer 0)
    proj_kernel<<<nbP, 256, 0, stream>>>(x, lin_w, lin_b, h16b0, bnpart, N);

    int cur = 0;
    _Float16* h16buf[2] = {h16b0, h16b1};
    int nbPart = nbP;   // partial count for current layer's BN

    for (int l = 0; l < 3; l++) {
        _Float16* h16c = h16buf[cur];
        _Float16* h16n = h16buf[cur ^ 1];
        bn_reduce_kernel<<<128, 256, 0, stream>>>(bnpart, nbPart, red);
        fold2_kernel<<<66, 256, 0, stream>>>(red,
                                             bn_gamma + l * 64, bn_beta + l * 64,
                                             conv_w + (size_t)l * 64 * 256,
                                             att_src + l * 256, att_dst + l * 256,
                                             Wt, bpb, Pt, cs, 1.f / (float)N);
        att_node_kernel<<<(N + 63) / 64, 256, 0, stream>>>(h16c, Pt, cs, a_sd, N);
        msg_proj_kernel<<<nTiles, 256, 0, stream>>>(row_ptr, src_csr,
                                                    ae_csr + (size_t)l * 4, a_sd,
                                                    h16c, Wt, bpb, conv_bias + l * 64,
                                                    h16n, bnpart, N);
        nbPart = nTiles;
        cur ^= 1;
    }

    pool_fc_kernel<<<(G + 3) / 4, 256, 0, stream>>>(h16buf[cur], gptr, fc1_w, fc1_b, fc2_w, fc2_b,
                                                    out, G);
}